// Round 1
// baseline (175.853 us; speedup 1.0000x reference)
//
#include <hip/hip_runtime.h>

static constexpr int BATCH = 65536;
static constexpr int DDIM  = 512;
static constexpr int NCLS  = 7;

struct WS {
  double sumsq;   // sum over all features^2
  double ce;      // sum of -logp[target]
  double l1;      // sum of |attention_weights|
  double pad;
  float  sums[NCLS * DDIM];  // per-class feature sums
  float  counts[NCLS];       // per-class counts
};

__device__ __forceinline__ float wave_reduce(float v) {
#pragma unroll
  for (int off = 32; off > 0; off >>= 1) v += __shfl_down(v, off);
  return v;
}

// Main streaming pass: features (class sums, counts, sum of squares) fused with
// L1 over attention_weights. One row per block-iteration; 256 threads cover
// D=512 as float2 per thread. Target is row-uniform -> scalar branch, named
// register accumulators (no runtime-indexed arrays -> no scratch).
__global__ __launch_bounds__(256) void k_main(const float* __restrict__ features,
                                              const int* __restrict__ targets,
                                              const float* __restrict__ aw,
                                              WS* __restrict__ ws) {
  const int tid = threadIdx.x;
  const float2* __restrict__ F = reinterpret_cast<const float2*>(features);
  const float2* __restrict__ A = reinterpret_cast<const float2*>(aw);

  float2 a0 = {0.f, 0.f}, a1 = {0.f, 0.f}, a2 = {0.f, 0.f}, a3 = {0.f, 0.f},
         a4 = {0.f, 0.f}, a5 = {0.f, 0.f}, a6 = {0.f, 0.f};
  float c0 = 0.f, c1 = 0.f, c2 = 0.f, c3 = 0.f, c4 = 0.f, c5 = 0.f, c6 = 0.f;
  float sumsq = 0.f, l1 = 0.f;

  for (int row = blockIdx.x; row < BATCH; row += gridDim.x) {
    const int t = __builtin_amdgcn_readfirstlane(targets[row]);
    const float2 f = F[row * (DDIM / 2) + tid];
    const float2 w = A[row * (DDIM / 2) + tid];
    sumsq = fmaf(f.x, f.x, sumsq);
    sumsq = fmaf(f.y, f.y, sumsq);
    l1 += fabsf(w.x) + fabsf(w.y);
    switch (t) {  // wave-uniform branch
      case 0: a0.x += f.x; a0.y += f.y; c0 += 1.f; break;
      case 1: a1.x += f.x; a1.y += f.y; c1 += 1.f; break;
      case 2: a2.x += f.x; a2.y += f.y; c2 += 1.f; break;
      case 3: a3.x += f.x; a3.y += f.y; c3 += 1.f; break;
      case 4: a4.x += f.x; a4.y += f.y; c4 += 1.f; break;
      case 5: a5.x += f.x; a5.y += f.y; c5 += 1.f; break;
      default: a6.x += f.x; a6.y += f.y; c6 += 1.f; break;
    }
  }

  // Merge per-class sums: each thread owns cols {2*tid, 2*tid+1}.
  const int col = 2 * tid;
  atomicAdd(&ws->sums[0 * DDIM + col], a0.x); atomicAdd(&ws->sums[0 * DDIM + col + 1], a0.y);
  atomicAdd(&ws->sums[1 * DDIM + col], a1.x); atomicAdd(&ws->sums[1 * DDIM + col + 1], a1.y);
  atomicAdd(&ws->sums[2 * DDIM + col], a2.x); atomicAdd(&ws->sums[2 * DDIM + col + 1], a2.y);
  atomicAdd(&ws->sums[3 * DDIM + col], a3.x); atomicAdd(&ws->sums[3 * DDIM + col + 1], a3.y);
  atomicAdd(&ws->sums[4 * DDIM + col], a4.x); atomicAdd(&ws->sums[4 * DDIM + col + 1], a4.y);
  atomicAdd(&ws->sums[5 * DDIM + col], a5.x); atomicAdd(&ws->sums[5 * DDIM + col + 1], a5.y);
  atomicAdd(&ws->sums[6 * DDIM + col], a6.x); atomicAdd(&ws->sums[6 * DDIM + col + 1], a6.y);

  __shared__ float lds[4];
  const int lane = tid & 63, wid = tid >> 6;

  float bs = wave_reduce(sumsq);
  if (lane == 0) lds[wid] = bs;
  __syncthreads();
  if (tid == 0) {
    atomicAdd(&ws->sumsq, (double)(lds[0] + lds[1] + lds[2] + lds[3]));
  }
  __syncthreads();

  float bl = wave_reduce(l1);
  if (lane == 0) lds[wid] = bl;
  __syncthreads();
  if (tid == 0) {
    atomicAdd(&ws->l1, (double)(lds[0] + lds[1] + lds[2] + lds[3]));
    // counts are block-uniform; thread 0 contributes once per block
    atomicAdd(&ws->counts[0], c0);
    atomicAdd(&ws->counts[1], c1);
    atomicAdd(&ws->counts[2], c2);
    atomicAdd(&ws->counts[3], c3);
    atomicAdd(&ws->counts[4], c4);
    atomicAdd(&ws->counts[5], c5);
    atomicAdd(&ws->counts[6], c6);
  }
}

// Cross-entropy over [B, 7] logits: one row per thread.
__global__ __launch_bounds__(256) void k_ce(const float* __restrict__ outputs,
                                            const int* __restrict__ targets,
                                            WS* __restrict__ ws) {
  float local = 0.f;
  for (int row = blockIdx.x * blockDim.x + threadIdx.x; row < BATCH;
       row += gridDim.x * blockDim.x) {
    const float* o = outputs + row * NCLS;
    const float x0 = o[0], x1 = o[1], x2 = o[2], x3 = o[3], x4 = o[4], x5 = o[5], x6 = o[6];
    const float m = fmaxf(fmaxf(fmaxf(x0, x1), fmaxf(x2, x3)),
                          fmaxf(fmaxf(x4, x5), x6));
    const float s = expf(x0 - m) + expf(x1 - m) + expf(x2 - m) + expf(x3 - m) +
                    expf(x4 - m) + expf(x5 - m) + expf(x6 - m);
    const int t = targets[row];
    const float xt = (t == 0) ? x0 : (t == 1) ? x1 : (t == 2) ? x2 :
                     (t == 3) ? x3 : (t == 4) ? x4 : (t == 5) ? x5 : x6;
    local += (m - xt) + logf(s);
  }
  __shared__ float lds[4];
  const int lane = threadIdx.x & 63, wid = threadIdx.x >> 6;
  float b = wave_reduce(local);
  if (lane == 0) lds[wid] = b;
  __syncthreads();
  if (threadIdx.x == 0) {
    atomicAdd(&ws->ce, (double)(lds[0] + lds[1] + lds[2] + lds[3]));
  }
}

// Finalize: WCSS identity + scalar combine. One block, 512 threads (one col each).
__global__ __launch_bounds__(512) void k_fin(const WS* __restrict__ ws,
                                             float* __restrict__ out) {
  const int tid = threadIdx.x;
  float partial = 0.f;
#pragma unroll
  for (int c = 0; c < NCLS; ++c) {
    const float cnt = ws->counts[c];
    const float s = ws->sums[c * DDIM + tid];
    partial += (cnt > 0.f) ? (s * s / cnt) : 0.f;
  }
  __shared__ float lds[8];
  const int lane = tid & 63, wid = tid >> 6;
  float b = wave_reduce(partial);
  if (lane == 0) lds[wid] = b;
  __syncthreads();
  if (tid == 0) {
    float wcss_sub = 0.f;
#pragma unroll
    for (int i = 0; i < 8; ++i) wcss_sub += lds[i];
    const double center = (ws->sumsq - (double)wcss_sub) / (double)BATCH;
    const double ce = ws->ce / (double)BATCH;
    const double l1 = ws->l1 / ((double)BATCH * (double)DDIM);
    const double total = ce + 0.1 * center + 0.01 * l1;
    out[0] = (float)total;
    out[1] = (float)ce;
    out[2] = (float)center;
    out[3] = (float)l1;
  }
}

extern "C" void kernel_launch(void* const* d_in, const int* in_sizes, int n_in,
                              void* d_out, int out_size, void* d_ws, size_t ws_size,
                              hipStream_t stream) {
  const float* outputs  = (const float*)d_in[0];
  const float* features = (const float*)d_in[1];
  const int*   targets  = (const int*)d_in[2];
  const float* aw       = (const float*)d_in[3];
  float* out = (float*)d_out;
  WS* ws = (WS*)d_ws;

  // Workspace accumulators must be zeroed every call (harness does not
  // re-poison between graph replays).
  hipMemsetAsync(d_ws, 0, sizeof(WS), stream);

  k_main<<<1024, 256, 0, stream>>>(features, targets, aw, ws);
  k_ce<<<256, 256, 0, stream>>>(outputs, targets, ws);
  k_fin<<<1, 512, 0, stream>>>(ws, out);
}